// Round 7
// baseline (908.279 us; speedup 1.0000x reference)
//
#include <hip/hip_runtime.h>
#include <hip/hip_cooperative_groups.h>
#include <math.h>

namespace cg = cooperative_groups;

#define NTOK 3136           // 16*14*14 tokens
#define MT 12544            // 4 * NTOK
#define KCV 2304            // 3*3*16*16
#define THRESH 1.5f
#define LN_EPS 1e-5f

typedef short short8 __attribute__((ext_vector_type(8)));
typedef float f32x4 __attribute__((ext_vector_type(4)));

// ---------- bf16 helpers (RTNE) ----------
__device__ __forceinline__ unsigned short f2bf(float f) {
    unsigned int u = __float_as_uint(f);
    u += 0x7fffu + ((u >> 16) & 1u);
    return (unsigned short)(u >> 16);
}
__device__ __forceinline__ float bf2f(unsigned short h) {
    return __uint_as_float(((unsigned int)h) << 16);
}
__device__ __forceinline__ void async16(const void* g, void* l) {
    __builtin_amdgcn_global_load_lds((const __attribute__((address_space(1))) void*)g,
                                     (__attribute__((address_space(3))) void*)l, 16, 0, 0);
}
__device__ __forceinline__ float wsum(float v) {
#pragma unroll
    for (int o = 32; o > 0; o >>= 1) v += __shfl_xor(v, o);
    return v;
}
__device__ __forceinline__ float wmax(float v) {
#pragma unroll
    for (int o = 32; o > 0; o >>= 1) v = fmaxf(v, __shfl_xor(v, o));
    return v;
}
__device__ __forceinline__ float q16sum(float v) {
    v += __shfl_xor(v, 1); v += __shfl_xor(v, 2);
    v += __shfl_xor(v, 4); v += __shfl_xor(v, 8);
    return v;
}

// ---------- prep: conv_w -> hi/lo bf16 ; wk, wv -> bf16 pool ----------
__global__ __launch_bounds__(256) void prep_k(
    const float* __restrict__ cw, unsigned short* __restrict__ cwh,
    unsigned short* __restrict__ cwl,
    const float* __restrict__ wk, const float* __restrict__ wv,
    unsigned short* __restrict__ pool)
{
    int i = blockIdx.x * 256 + threadIdx.x;
    if (i < 589824) {
        float a = cw[i];
        unsigned short h = f2bf(a);
        cwh[i] = h;
        cwl[i] = f2bf(a - bf2f(h));
        return;
    }
    int j = i - 589824;
    if (j >= 131072) return;
    pool[j] = f2bf(j < 65536 ? wk[j] : wv[j - 65536]);
}

// ---------- conv implicit GEMM, software-pipelined (R5, verified) ----------
__global__ __launch_bounds__(256) void conv_pipe_k(
    const float* __restrict__ video, const unsigned short* __restrict__ cwh,
    const unsigned short* __restrict__ cwl, const float* __restrict__ cb,
    float* __restrict__ outF, unsigned short* __restrict__ outB)
{
    __shared__ __align__(16) unsigned short Ah[2][2048], Al[2][2048];
    __shared__ __align__(16) unsigned short Bh[2][2048], Bl[2][2048];
    const int t    = threadIdx.x;
    const int lane = t & 63;
    const int w    = t >> 6;
    const int m0   = blockIdx.x * 64;
    const int e0   = blockIdx.y * 64;
    const int l15  = lane & 15, lq = lane >> 4;
    const bool isb0 = (blockIdx.x < 49);

    int m = m0 + lane;
    int b = m / NTOK, n = m % NTOK;
    int d = n / 196, hw = n % 196;
    int h = hw / 14, ww = hw % 14;
    const float* vb = video + (size_t)b * 4816896 + (h * 16) * 224 + ww * 16;
    int dbase = 2 * d - 1;
    const unsigned short* bhrow = cwh + (size_t)(e0 + lane) * KCV;
    const unsigned short* blrow = cwl + (size_t)(e0 + lane) * KCV;

    auto loadA = [&](int step, float4& a0, float4& a1) {
        int k0  = step * 32 + w * 8;
        int c   = k0 / 768;
        int rem = k0 - c * 768;
        int kd  = rem >> 8;
        int r2  = rem & 255;
        int id  = dbase + kd;
        a0 = make_float4(0.f, 0.f, 0.f, 0.f); a1 = a0;
        if (id >= 0) {
            const float* p = vb + (size_t)c * 1605632 + id * 50176 + (r2 >> 4) * 224 + (r2 & 15);
            a0 = *(const float4*)p;
            a1 = *(const float4*)(p + 4);
        }
    };
    auto issueB = [&](int step, int buf) {
        int k0 = step * 32 + w * 8;
        async16(bhrow + k0, &Bh[buf][w * 512]);
        if (isb0) async16(blrow + k0, &Bl[buf][w * 512]);
    };
    auto packA = [&](int buf, float4 a0, float4 a1) {
        float av[8] = {a0.x, a0.y, a0.z, a0.w, a1.x, a1.y, a1.z, a1.w};
        unsigned int ph[4];
        unsigned short hi[8];
#pragma unroll
        for (int j = 0; j < 4; ++j) {
            hi[2 * j]     = f2bf(av[2 * j]);
            hi[2 * j + 1] = f2bf(av[2 * j + 1]);
            ph[j] = (unsigned int)hi[2 * j] | ((unsigned int)hi[2 * j + 1] << 16);
        }
        *(uint4*)&Ah[buf][lane * 8 + w * 512] = make_uint4(ph[0], ph[1], ph[2], ph[3]);
        if (isb0) {
            unsigned int pl[4];
#pragma unroll
            for (int j = 0; j < 4; ++j) {
                unsigned short q0 = f2bf(av[2 * j]     - bf2f(hi[2 * j]));
                unsigned short q1 = f2bf(av[2 * j + 1] - bf2f(hi[2 * j + 1]));
                pl[j] = (unsigned int)q0 | ((unsigned int)q1 << 16);
            }
            *(uint4*)&Al[buf][lane * 8 + w * 512] = make_uint4(pl[0], pl[1], pl[2], pl[3]);
        }
    };

    f32x4 acc[4] = {};
    auto doMfma = [&](int buf) {
        short8 fah = *(const short8*)&Ah[buf][(lq * 64 + w * 16 + l15) * 8];
        if (isb0) {
            short8 fal = *(const short8*)&Al[buf][(lq * 64 + w * 16 + l15) * 8];
#pragma unroll
            for (int ct = 0; ct < 4; ++ct) {
                short8 fbh = *(const short8*)&Bh[buf][(lq * 64 + ct * 16 + l15) * 8];
                short8 fbl = *(const short8*)&Bl[buf][(lq * 64 + ct * 16 + l15) * 8];
                acc[ct] = __builtin_amdgcn_mfma_f32_16x16x32_bf16(fah, fbh, acc[ct], 0, 0, 0);
                acc[ct] = __builtin_amdgcn_mfma_f32_16x16x32_bf16(fah, fbl, acc[ct], 0, 0, 0);
                acc[ct] = __builtin_amdgcn_mfma_f32_16x16x32_bf16(fal, fbh, acc[ct], 0, 0, 0);
            }
        } else {
#pragma unroll
            for (int ct = 0; ct < 4; ++ct) {
                short8 fbh = *(const short8*)&Bh[buf][(lq * 64 + ct * 16 + l15) * 8];
                acc[ct] = __builtin_amdgcn_mfma_f32_16x16x32_bf16(fah, fbh, acc[ct], 0, 0, 0);
            }
        }
    };

    float4 a0c, a1c;
    loadA(0, a0c, a1c);
    issueB(0, 0);
    packA(0, a0c, a1c);
    __syncthreads();
    for (int step = 0; step < 71; ++step) {
        int cur = step & 1, nxt = cur ^ 1;
        float4 a0n, a1n;
        loadA(step + 1, a0n, a1n);
        issueB(step + 1, nxt);
        doMfma(cur);
        packA(nxt, a0n, a1n);
        __syncthreads();
    }
    doMfma(1);

    int rbase = m0 + w * 16 + lq * 4;
#pragma unroll
    for (int ct = 0; ct < 4; ++ct) {
        int e = e0 + ct * 16 + l15;
        float bias = cb[e];
#pragma unroll
        for (int r = 0; r < 4; ++r) {
            float v = fmaxf(acc[ct][r] + bias, 0.f);
            size_t off = (size_t)(rbase + r) * 256 + e;
            if (isb0) outF[off] = v;
            outB[off] = f2bf(v);
        }
    }
}

// ================= shared tile functions =================
struct MA {
    const float *Wd, *Wo, *bo, *bd, *q0, *Wb, *bb;
    const float *inW, *inB;
    const float *wq_w, *wq_b, *lnq_g, *lnq_b;
    const float *lnk_g, *lnk_b, *lnv_g, *lnv_b, *wk_b, *wv_b;
    const float *ent;
    const float *W1f;
    const unsigned short *pool;
    unsigned short *B1;
    unsigned short *B3;
    unsigned short *W4;
    float *T, *T2, *u, *bc2, *bcomb2, *qpre, *U, *cvec, *sc;
    int *boundary, *seg_start, *Sp;
    float *out;
};

__device__ void boundary_tile(int tl, const MA& a) {
    const int t = threadIdx.x, lane = t & 63, w = t >> 6;
    int n = tl * 4 + w;
    const float4 x = reinterpret_cast<const float4*>(a.W1f + (size_t)n * 256)[lane];
    float mean = wsum(x.x + x.y + x.z + x.w) * (1.f / 256.f);
    float bf = rintf(mean * 255.f);
    bf = fminf(fmaxf(bf, 0.f), 255.f);
    int byte = (int)bf;
    const float4 lg = reinterpret_cast<const float4*>(a.ent + byte * 256)[lane];
    float mx = wmax(fmaxf(fmaxf(lg.x, lg.y), fmaxf(lg.z, lg.w)));
    float e0 = expf(lg.x - mx), e1 = expf(lg.y - mx), e2 = expf(lg.z - mx), e3 = expf(lg.w - mx);
    float z = wsum(e0 + e1 + e2 + e3);
    float iz = 1.f / z;
    float p0 = e0 * iz, p1 = e1 * iz, p2 = e2 * iz, p3 = e3 * iz;
    float ep = -(p0 * log2f(p0 + 1e-9f) + p1 * log2f(p1 + 1e-9f) +
                 p2 * log2f(p2 + 1e-9f) + p3 * log2f(p3 + 1e-9f));
    ep = wsum(ep);
    if (lane == 0) a.boundary[n] = (ep > THRESH) ? 1 : 0;
}

__device__ void foldT_tile(int f, const MA& a) {
    const int t = threadIdx.x;
    float acc = 0.f;
    const float* wdr = a.Wd + (size_t)f * 256;
#pragma unroll 4
    for (int e = 0; e < 256; ++e) acc += wdr[e] * a.Wo[(size_t)e * 256 + t];
    a.T[(size_t)f * 256 + t] = acc;
}
__device__ void u_tile(const MA& a) {
    const int t = threadIdx.x, w = t >> 6, lane = t & 63;
    float4 b4 = reinterpret_cast<const float4*>(a.bo)[lane];
    for (int i = 0; i < 64; ++i) {
        int row = w * 64 + i;
        float4 w4 = reinterpret_cast<const float4*>(a.Wd + (size_t)row * 256)[lane];
        float pv = wsum(w4.x * b4.x + w4.y * b4.y + w4.z * b4.z + w4.w * b4.w);
        if (lane == 0) a.u[row] = pv + a.bd[row] + a.q0[row];
    }
}
__device__ void qpre_tile(int q, const MA& a) {
    const int t = threadIdx.x, w = t >> 6, lane = t & 63;
    float4 g4 = reinterpret_cast<const float4*>(a.q0)[lane];
    for (int i = 0; i < 16; ++i) {
        int row = q * 64 + w * 16 + i;
        float4 wr = reinterpret_cast<const float4*>(a.wq_w + (size_t)row * 256)[lane];
        float pv = wsum(g4.x * wr.x + g4.y * wr.y + g4.z * wr.z + g4.w * wr.w);
        if (lane == 0) a.qpre[row] = pv + a.wq_b[row];
    }
}
__device__ void fold2_tile(int f, const MA& a) {
    const int t = threadIdx.x;
    float acc = 0.f;
    const float* wbr = a.Wb + (size_t)f * 256;
#pragma unroll 4
    for (int e = 0; e < 256; ++e) acc += wbr[e] * a.T[(size_t)e * 256 + t];
    a.T2[(size_t)f * 256 + t] = acc;
}
__device__ void bc2_tile(const MA& a) {
    const int t = threadIdx.x, w = t >> 6, lane = t & 63;
    float4 u4 = reinterpret_cast<const float4*>(a.u)[lane];
    for (int i = 0; i < 64; ++i) {
        int row = w * 64 + i;
        float4 w4 = reinterpret_cast<const float4*>(a.Wb + (size_t)row * 256)[lane];
        float pv = wsum(w4.x * u4.x + w4.y * u4.y + w4.z * u4.z + w4.w * u4.w);
        if (lane == 0) a.bc2[row] = pv + a.bb[row];
    }
}
__device__ void scan_tile(const MA& a, int* sums) {
    const int t = threadIdx.x;
    const int CH = 13;
    int base = t * CH;
    int s = 0;
    for (int i = 0; i < CH; i++) { int n = base + i; if (n < NTOK) s += a.boundary[n]; }
    sums[t] = s; __syncthreads();
    for (int o = 1; o < 256; o <<= 1) {
        int v = sums[t];
        int u = (t >= o) ? sums[t - o] : 0;
        __syncthreads();
        sums[t] = v + u;
        __syncthreads();
    }
    int run = (t == 0) ? 0 : sums[t - 1];
    if (t == 0) a.seg_start[0] = 0;
    for (int i = 0; i < CH; i++) {
        int n = base + i;
        if (n >= NTOK) break;
        int v = a.boundary[n];
        if (n == NTOK - 1) { a.Sp[0] = run + 1; a.seg_start[run + 1] = NTOK; }
        if (v && (n + 1 < NTOK)) a.seg_start[run + 1] = n + 1;
        run += v;
    }
}
__device__ void q2_tile(const MA& a, float* sm) {
    float* sh  = sm;
    float* qpL = sm + 256;
    float* red = sm + 512;
    const int t = threadIdx.x, w = t >> 6, lane = t & 63;
    float acc = a.qpre[t];
    red[t] = acc; __syncthreads();
    for (int o = 128; o > 0; o >>= 1) { if (t < o) red[t] += red[t + o]; __syncthreads(); }
    float m = red[0] * (1.f / 256.f);
    __syncthreads();
    float dd = acc - m;
    red[t] = dd * dd; __syncthreads();
    for (int o = 128; o > 0; o >>= 1) { if (t < o) red[t] += red[t + o]; __syncthreads(); }
    float inv = 1.f / sqrtf(red[0] * (1.f / 256.f) + LN_EPS);
    __syncthreads();
    sh[t] = dd * inv * a.lnq_g[t] + a.lnq_b[t];
    __syncthreads();
    float4 s4 = reinterpret_cast<const float4*>(sh)[lane];
    for (int i = 0; i < 64; ++i) {
        int row = w * 64 + i;
        float4 wr = reinterpret_cast<const float4*>(a.inW + (size_t)row * 256)[lane];
        float pv = wsum(s4.x * wr.x + s4.y * wr.y + s4.z * wr.z + s4.w * wr.w);
        if (lane == 0) qpL[row] = (pv + a.inB[row]) * 0.125f;
    }
    __syncthreads();
    const float* Wki = a.inW + 65536;
    const float* bki = a.inB + 256;
#pragma unroll
    for (int h = 0; h < 4; ++h) {
        float a2 = 0.f;
        for (int e = 0; e < 64; ++e)
            a2 += qpL[h * 64 + e] * Wki[(size_t)(h * 64 + e) * 256 + t];
        a.U[h * 256 + t] = a2;
    }
    float cv = wsum(qpL[t] * bki[t]);
    if (lane == 0) a.cvec[w] = cv;
}

// K/V projection tile (64 rows x 256 cols), LN fused; K also emits scores.
__device__ void gemm_ln_tile(int m0, bool isK, const MA& a,
                             unsigned short* As, unsigned short* Bs0, unsigned short* Bs1)
{
    const int t = threadIdx.x, lane = t & 63, w = t >> 6;
    const int l15 = lane & 15, lq = lane >> 4;
    const unsigned short* Wp = isK ? a.pool : a.pool + 65536;
    f32x4 acc[4][4] = {};
    for (int kh = 0; kh < 2; ++kh) {
#pragma unroll
        for (int kg = w; kg < 16; kg += 4) {
            async16(a.B1 + (size_t)(m0 + lane) * 256 + kh * 128 + kg * 8, &As[kg * 512]);
            async16(Wp + (size_t)lane * 256 + kh * 128 + kg * 8, &Bs0[kg * 512]);
        }
        __syncthreads();
#pragma unroll
        for (int eg = 0; eg < 4; ++eg) {
            unsigned short* cur = (eg & 1) ? Bs1 : Bs0;
            unsigned short* nxt = (eg & 1) ? Bs0 : Bs1;
            if (eg < 3) {
#pragma unroll
                for (int kg = w; kg < 16; kg += 4)
                    async16(Wp + (size_t)((eg + 1) * 64 + lane) * 256 + kh * 128 + kg * 8,
                            &nxt[kg * 512]);
            }
#pragma unroll
            for (int s = 0; s < 4; ++s) {
                int kg = s * 4 + lq;
                short8 av = *(const short8*)&As[(kg * 64 + w * 16 + l15) * 8];
#pragma unroll
                for (int ct = 0; ct < 4; ++ct) {
                    short8 bv = *(const short8*)&cur[(kg * 64 + ct * 16 + l15) * 8];
                    acc[eg][ct] = __builtin_amdgcn_mfma_f32_16x16x32_bf16(av, bv, acc[eg][ct], 0, 0, 0);
                }
            }
            __syncthreads();
        }
    }
    const float* bias = isK ? a.wk_b : a.wv_b;
    const float* lng  = isK ? a.lnk_g : a.lnv_g;
    const float* lnb  = isK ? a.lnk_b : a.lnv_b;
#pragma unroll
    for (int eg = 0; eg < 4; ++eg)
#pragma unroll
        for (int ct = 0; ct < 4; ++ct) {
            float bv = bias[eg * 64 + ct * 16 + l15];
#pragma unroll
            for (int r = 0; r < 4; ++r) acc[eg][ct][r] += bv;
        }
    float mean[4], inv[4];
#pragma unroll
    for (int r = 0; r < 4; ++r) {
        float s1 = 0.f;
#pragma unroll
        for (int eg = 0; eg < 4; ++eg)
#pragma unroll
            for (int ct = 0; ct < 4; ++ct) s1 += acc[eg][ct][r];
        mean[r] = q16sum(s1) * (1.f / 256.f);
    }
#pragma unroll
    for (int r = 0; r < 4; ++r) {
        float s2 = 0.f;
#pragma unroll
        for (int eg = 0; eg < 4; ++eg)
#pragma unroll
            for (int ct = 0; ct < 4; ++ct) {
                float d = acc[eg][ct][r] - mean[r];
                s2 += d * d;
            }
        inv[r] = 1.f / sqrtf(q16sum(s2) * (1.f / 256.f) + LN_EPS);
    }
    int rbase = m0 + w * 16 + lq * 4;
    if (isK) {
        float p[4][4] = {};
#pragma unroll
        for (int eg = 0; eg < 4; ++eg)
#pragma unroll
            for (int ct = 0; ct < 4; ++ct) {
                int e = eg * 64 + ct * 16 + l15;
                float ge = lng[e], be = lnb[e];
                float u0 = a.U[e], u1 = a.U[256 + e], u2 = a.U[512 + e], u3 = a.U[768 + e];
#pragma unroll
                for (int r = 0; r < 4; ++r) {
                    float kl = (acc[eg][ct][r] - mean[r]) * inv[r] * ge + be;
                    p[0][r] += kl * u0; p[1][r] += kl * u1;
                    p[2][r] += kl * u2; p[3][r] += kl * u3;
                }
            }
#pragma unroll
        for (int h = 0; h < 4; ++h)
#pragma unroll
            for (int r = 0; r < 4; ++r) p[h][r] = q16sum(p[h][r]);
        if (l15 == 0) {
#pragma unroll
            for (int r = 0; r < 4; ++r) {
                int mm = rbase + r;
                int b = mm / NTOK, n = mm % NTOK;
#pragma unroll
                for (int h = 0; h < 4; ++h)
                    a.sc[(size_t)(b * 4 + h) * NTOK + n] = p[h][r] + a.cvec[h];
            }
        }
    } else {
#pragma unroll
        for (int eg = 0; eg < 4; ++eg)
#pragma unroll
            for (int ct = 0; ct < 4; ++ct) {
                int e = eg * 64 + ct * 16 + l15;
                float ge = lng[e], be = lnb[e];
#pragma unroll
                for (int r = 0; r < 4; ++r)
                    a.B3[(size_t)(rbase + r) * 256 + e] =
                        f2bf((acc[eg][ct][r] - mean[r]) * inv[r] * ge + be);
            }
    }
}

__device__ void fold3_tile(int f, const MA& a) {
    const int t = threadIdx.x;
    float acc = 0.f;
    const float* t2r = a.T2 + (size_t)f * 256;
#pragma unroll 4
    for (int i = 0; i < 256; ++i) acc += t2r[i] * a.inW[(size_t)(512 + i) * 256 + t];
    a.W4[(size_t)f * 256 + t] = f2bf(acc);
}
__device__ void bcomb2_tile(const MA& a) {
    const int t = threadIdx.x, w = t >> 6, lane = t & 63;
    float4 b4 = reinterpret_cast<const float4*>(a.inB + 512)[lane];
    for (int i = 0; i < 64; ++i) {
        int row = w * 64 + i;
        float4 w4 = reinterpret_cast<const float4*>(a.T2 + (size_t)row * 256)[lane];
        float pv = wsum(w4.x * b4.x + w4.y * b4.y + w4.z * b4.z + w4.w * b4.w);
        if (lane == 0) a.bcomb2[row] = pv + a.bc2[row];
    }
}
__device__ void attn_tile(int s, int h, const MA& a) {
    const int b = threadIdx.x >> 6, lane = threadIdx.x & 63;
    unsigned short* orow = a.B1 + ((size_t)b * NTOK + s) * 256 + h * 64;
    int S = *a.Sp;
    if (s >= S) { orow[lane] = 0; return; }
    int st = a.seg_start[s], en = a.seg_start[s + 1];
    const float* scr = a.sc + (size_t)(b * 4 + h) * NTOK;
    float m = -1e30f;
    for (int n = st; n < en; n++) m = fmaxf(m, scr[n]);
    float den = 0.f, acc = 0.f;
    for (int n = st; n < en; n++) {
        float wgt = expf(scr[n] - m);
        den += wgt;
        acc += wgt * bf2f(a.B3[((size_t)b * NTOK + n) * 256 + h * 64 + lane]);
    }
    orow[lane] = f2bf(acc / den);
}
__device__ void final_tile(int m0, int e0, const MA& a, unsigned short* As, unsigned short* Bs) {
    const int t = threadIdx.x, lane = t & 63, w = t >> 6;
    const int l15 = lane & 15, lq = lane >> 4;
    f32x4 acc[4] = {};
    for (int kh = 0; kh < 2; ++kh) {
#pragma unroll
        for (int kg = w; kg < 16; kg += 4) {
            async16(a.B1 + (size_t)(m0 + lane) * 256 + kh * 128 + kg * 8, &As[kg * 512]);
            async16(a.W4 + (size_t)(e0 + lane) * 256 + kh * 128 + kg * 8, &Bs[kg * 512]);
        }
        __syncthreads();
#pragma unroll
        for (int s = 0; s < 4; ++s) {
            int kg = s * 4 + lq;
            short8 av = *(const short8*)&As[(kg * 64 + w * 16 + l15) * 8];
#pragma unroll
            for (int ct = 0; ct < 4; ++ct) {
                short8 bv = *(const short8*)&Bs[(kg * 64 + ct * 16 + l15) * 8];
                acc[ct] = __builtin_amdgcn_mfma_f32_16x16x32_bf16(av, bv, acc[ct], 0, 0, 0);
            }
        }
        __syncthreads();
    }
    int S = *a.Sp;
    int rbase = m0 + w * 16 + lq * 4;
#pragma unroll
    for (int ct = 0; ct < 4; ++ct) {
        int e = e0 + ct * 16 + l15;
        float bv = a.bcomb2[e];
#pragma unroll
        for (int r = 0; r < 4; ++r) {
            int mm = rbase + r;
            float v = acc[ct][r] + bv;
            if ((mm % NTOK) >= S) v = 0.f;
            a.out[(size_t)mm * 256 + e] = v;
        }
    }
}

// ================= cooperative mega kernel =================
__global__ __launch_bounds__(256, 3) void mega_k(MA a) {
    cg::grid_group gg = cg::this_grid();
    __shared__ __align__(16) unsigned short smem[24576];   // 48 KB
    unsigned short* As  = smem;
    unsigned short* Bs0 = smem + 8192;
    unsigned short* Bs1 = smem + 16384;
    const int nb = gridDim.x;

    for (int tl = blockIdx.x; tl < 1045; tl += nb) {
        if (tl < 784) boundary_tile(tl, a);
        else if (tl < 1040) foldT_tile(tl - 784, a);
        else if (tl == 1040) u_tile(a);
        else qpre_tile(tl - 1041, a);
    }
    gg.sync();
    for (int tl = blockIdx.x; tl < 259; tl += nb) {
        if (tl < 256) fold2_tile(tl, a);
        else if (tl == 256) bc2_tile(a);
        else if (tl == 257) scan_tile(a, (int*)smem);
        else q2_tile(a, (float*)smem);
    }
    gg.sync();
    for (int tl = blockIdx.x; tl < 649; tl += nb) {
        if (tl < 196) gemm_ln_tile(tl * 64, true, a, As, Bs0, Bs1);
        else if (tl < 392) gemm_ln_tile((tl - 196) * 64, false, a, As, Bs0, Bs1);
        else if (tl < 648) fold3_tile(tl - 392, a);
        else bcomb2_tile(a);
    }
    gg.sync();
    for (int tl = blockIdx.x; tl < 12544; tl += nb) attn_tile(tl >> 2, tl & 3, a);
    gg.sync();
    for (int tl = blockIdx.x; tl < 784; tl += nb)
        final_tile((tl >> 2) * 64, (tl & 3) * 64, a, As, Bs0);
}

// ================= fallback: stage wrappers (plain kernels) =================
__global__ __launch_bounds__(256) void s0_k(MA a) {
    int tl = blockIdx.x;
    if (tl < 784) boundary_tile(tl, a);
    else if (tl < 1040) foldT_tile(tl - 784, a);
    else if (tl == 1040) u_tile(a);
    else qpre_tile(tl - 1041, a);
}
__global__ __launch_bounds__(256) void s1_k(MA a) {
    __shared__ __align__(16) float sm[768];
    int tl = blockIdx.x;
    if (tl < 256) fold2_tile(tl, a);
    else if (tl == 256) bc2_tile(a);
    else if (tl == 257) scan_tile(a, (int*)sm);
    else q2_tile(a, sm);
}
__global__ __launch_bounds__(256) void s2_k(MA a) {
    __shared__ __align__(16) unsigned short smem[24576];
    int tl = blockIdx.x;
    if (tl < 196) gemm_ln_tile(tl * 64, true, a, smem, smem + 8192, smem + 16384);
    else if (tl < 392) gemm_ln_tile((tl - 196) * 64, false, a, smem, smem + 8192, smem + 16384);
    else if (tl < 648) fold3_tile(tl - 392, a);
    else bcomb2_tile(a);
}
__global__ __launch_bounds__(256) void s3_k(MA a) {
    int tl = blockIdx.x;
    attn_tile(tl >> 2, tl & 3, a);
}
__global__ __launch_bounds__(256) void s4_k(MA a) {
    __shared__ __align__(16) unsigned short smem[16384];
    int tl = blockIdx.x;
    final_tile((tl >> 2) * 64, (tl & 3) * 64, a, smem, smem + 8192);
}

extern "C" void kernel_launch(void* const* d_in, const int* in_sizes, int n_in,
                              void* d_out, int out_size, void* d_ws, size_t ws_size,
                              hipStream_t stream)
{
    const float* video      = (const float*)d_in[0];
    const float* conv_w     = (const float*)d_in[1];
    const float* conv_b     = (const float*)d_in[2];
    const float* wq_w       = (const float*)d_in[3];
    const float* wq_b       = (const float*)d_in[4];
    const float* wk_w       = (const float*)d_in[5];
    const float* wk_b       = (const float*)d_in[6];
    const float* wv_w       = (const float*)d_in[7];
    const float* wv_b       = (const float*)d_in[8];
    const float* lnq_g      = (const float*)d_in[9];
    const float* lnq_b      = (const float*)d_in[10];
    const float* lnk_g      = (const float*)d_in[11];
    const float* lnk_b      = (const float*)d_in[12];
    const float* lnv_g      = (const float*)d_in[13];
    const float* lnv_b      = (const float*)d_in[14];
    const float* in_proj_w  = (const float*)d_in[15];
    const float* in_proj_b  = (const float*)d_in[16];
    const float* out_proj_w = (const float*)d_in[17];
    const float* out_proj_b = (const float*)d_in[18];
    const float* dense_w    = (const float*)d_in[19];
    const float* dense_b    = (const float*)d_in[20];
    const float* bproj_w    = (const float*)d_in[21];
    const float* bproj_b    = (const float*)d_in[22];
    const float* group_q    = (const float*)d_in[23];
    const float* ent_table  = (const float*)d_in[24];

    float* W1f = (float*)d_ws;
    unsigned short* B1  = (unsigned short*)(W1f + (size_t)MT * 256);
    unsigned short* B3  = B1 + (size_t)MT * 256;
    unsigned short* cwh = B3 + (size_t)MT * 256;
    unsigned short* cwl = cwh + 589824;
    unsigned short* pool = cwl + 589824;
    unsigned short* W4   = pool + 131072;
    float* T    = (float*)(W4 + 65536);
    float* T2   = T + 65536;
    float* u    = T2 + 65536;
    float* bc2  = u + 256;
    float* bcomb2 = bc2 + 256;
    float* qpre = bcomb2 + 256;
    float* U    = qpre + 256;
    float* cvec = U + 1024;
    float* sc   = cvec + 8;
    int* boundary  = (int*)(sc + 16 * NTOK);
    int* seg_start = boundary + NTOK;
    int* Sp        = seg_start + (NTOK + 1);

    dim3 blk(256);
    prep_k<<<dim3(2816), blk, 0, stream>>>(conv_w, cwh, cwl, wk_w, wv_w, pool);
    conv_pipe_k<<<dim3(196, 4), blk, 0, stream>>>(video, cwh, cwl, conv_b, W1f, B1);

    MA a;
    a.Wd = dense_w; a.Wo = out_proj_w; a.bo = out_proj_b; a.bd = dense_b;
    a.q0 = group_q; a.Wb = bproj_w; a.bb = bproj_b;
    a.inW = in_proj_w; a.inB = in_proj_b;
    a.wq_w = wq_w; a.wq_b = wq_b; a.lnq_g = lnq_g; a.lnq_b = lnq_b;
    a.lnk_g = lnk_g; a.lnk_b = lnk_b; a.lnv_g = lnv_g; a.lnv_b = lnv_b;
    a.wk_b = wk_b; a.wv_b = wv_b; a.ent = ent_table;
    a.W1f = W1f; a.pool = pool; a.B1 = B1; a.B3 = B3; a.W4 = W4;
    a.T = T; a.T2 = T2; a.u = u; a.bc2 = bc2; a.bcomb2 = bcomb2;
    a.qpre = qpre; a.U = U; a.cvec = cvec; a.sc = sc;
    a.boundary = boundary; a.seg_start = seg_start; a.Sp = Sp;
    a.out = (float*)d_out;

    // cooperative path: clamp grid to queried occupancy, check launch result
    int occ = 0;
    hipError_t e = hipOccupancyMaxActiveBlocksPerMultiprocessor(&occ, (const void*)mega_k, 256, 0);
    bool coop_ok = false;
    if (e == hipSuccess && occ > 0) {
        int grid = occ * 256;               // 256 CUs on MI355X
        if (grid > 768) grid = 768;
        void* kargs[] = { &a };
        hipError_t le = hipLaunchCooperativeKernel((const void*)mega_k, dim3(grid), dim3(256),
                                                   kargs, 0, stream);
        coop_ok = (le == hipSuccess);
    }
    if (!coop_ok) {
        s0_k<<<dim3(1045), blk, 0, stream>>>(a);
        s1_k<<<dim3(259),  blk, 0, stream>>>(a);
        s2_k<<<dim3(649),  blk, 0, stream>>>(a);
        s3_k<<<dim3(12544), blk, 0, stream>>>(a);
        s4_k<<<dim3(784),  blk, 0, stream>>>(a);
    }
}